// Round 1
// 81.856 us; speedup vs baseline: 1.0096x; 1.0096x over previous
//
#include <hip/hip_runtime.h>
#include <math.h>

#define BATCH  8
#define NPTS   4096
#define TPB    256
#define QPT    8                 // queries per thread (independent min chains)
#define QCHUNK (TPB * QPT)       // 2048 queries per block
#define NQC    (NPTS / QCHUNK)   // 2 query chunks
#define NCC    32                // candidate chunks (parallelism multiplier)
#define CTILE  (NPTS / NCC)      // 128 candidates per chunk

// Phase 1: block = (query chunk qc, candidate chunk cc, batch, dir).
// Candidates staged in LDS as (-2cx, -2cy, -2cz, ||c||^2) so each pair costs
// 3 FMA + 1 min. QPT=8 gives a 32:1 VALU:LDS-read ratio (was 16:1), keeping
// the per-CU LDS pipe off the critical path. No atomics: each block writes
// its partial minima (x2-added, clamped) to part[dir][b][cc][q] — coalesced
// float4 stores — and phase 2 min-reduces over cc. This removes the 1M
// device-scope atomicMin ops and the 256 KB pattern-memset.
__global__ __launch_bounds__(TPB) void chamfer_min_kernel(
    const float* __restrict__ input,
    const float* __restrict__ target,
    float* __restrict__ part)   // [2][BATCH][NCC][NPTS] floats = 8 MB
{
    const int dir = blockIdx.z;
    const int b   = blockIdx.y;
    const int qc  = blockIdx.x & (NQC - 1);
    const int cc  = blockIdx.x >> 1;          // NQC == 2

    const float* __restrict__ qp = (dir ? target : input) + (size_t)b * NPTS * 3;
    const float* __restrict__ cp = (dir ? input  : target) + (size_t)b * NPTS * 3;

    __shared__ float4 cand[CTILE];
    if (threadIdx.x < CTILE) {                // CTILE == 128
        const int c = cc * CTILE + threadIdx.x;
        const float cx = cp[3 * c + 0];
        const float cy = cp[3 * c + 1];
        const float cz = cp[3 * c + 2];
        cand[threadIdx.x] = make_float4(-2.0f * cx, -2.0f * cy, -2.0f * cz,
                                        fmaf(cx, cx, fmaf(cy, cy, cz * cz)));
    }

    // 8 contiguous queries per thread = 24 contiguous floats = 6 float4 loads.
    // Byte offset 96*tid is 16B-aligned.
    const int q0 = qc * QCHUNK + (int)threadIdx.x * QPT;
    float v[3 * QPT];
    const float4* __restrict__ qv = (const float4*)(qp + 3 * q0);
    #pragma unroll
    for (int i = 0; i < 6; ++i) {
        const float4 t = qv[i];
        v[4 * i + 0] = t.x; v[4 * i + 1] = t.y;
        v[4 * i + 2] = t.z; v[4 * i + 3] = t.w;
    }
    float px[QPT], py[QPT], pz[QPT], pmin[QPT];
    #pragma unroll
    for (int k = 0; k < QPT; ++k) {
        px[k] = v[3 * k + 0];
        py[k] = v[3 * k + 1];
        pz[k] = v[3 * k + 2];
        pmin[k] = 3.4e38f;
    }
    __syncthreads();

    #pragma unroll 8
    for (int m = 0; m < CTILE; ++m) {
        const float4 c = cand[m];                 // LDS broadcast read (uniform addr)
        #pragma unroll
        for (int k = 0; k < QPT; ++k) {
            const float t = fmaf(px[k], c.x,
                            fmaf(py[k], c.y,
                            fmaf(pz[k], c.z, c.w)));   // ||c||^2 - 2 x.c
            pmin[k] = fminf(pmin[k], t);
        }
    }

    // ||x||^2 is monotone-safe to add after the min; clamp matches ref.
    float res[QPT];
    #pragma unroll
    for (int k = 0; k < QPT; ++k) {
        const float x2 = fmaf(px[k], px[k], fmaf(py[k], py[k], pz[k] * pz[k]));
        res[k] = fmaxf(pmin[k] + x2, 0.0f);
    }
    float* o = part + (((size_t)(dir * BATCH + b) * NCC + cc) * NPTS + q0);
    *(float4*)(o + 0) = make_float4(res[0], res[1], res[2], res[3]);
    *(float4*)(o + 4) = make_float4(res[4], res[5], res[6], res[7]);
}

// Phase 2: for each of 2*BATCH*NPTS = 65536 outputs, min over NCC=32 partials,
// then sum-reduce -> mean(dir0)+mean(dir1). 8 MB coalesced reads.
__global__ __launch_bounds__(TPB) void chamfer_reduce_kernel(
    const float* __restrict__ part, float* __restrict__ out)
{
    const int i = (blockIdx.x * TPB + (int)threadIdx.x) * 4;   // [2][B][NPTS] flat
    const int g = i >> 12;                                     // / NPTS (0..15)
    const int q = i & (NPTS - 1);
    const float* __restrict__ p = part + ((size_t)g * NCC) * NPTS + q;

    float4 mn = *(const float4*)p;
    #pragma unroll 8
    for (int cc = 1; cc < NCC; ++cc) {
        const float4 t = *(const float4*)(p + (size_t)cc * NPTS);
        mn.x = fminf(mn.x, t.x); mn.y = fminf(mn.y, t.y);
        mn.z = fminf(mn.z, t.z); mn.w = fminf(mn.w, t.w);
    }
    float s = mn.x + mn.y + mn.z + mn.w;
    #pragma unroll
    for (int off = 32; off > 0; off >>= 1)
        s += __shfl_down(s, off, 64);

    __shared__ float wsum[TPB / 64];
    if ((threadIdx.x & 63) == 0) wsum[threadIdx.x >> 6] = s;
    __syncthreads();
    if (threadIdx.x == 0) {
        const float t = wsum[0] + wsum[1] + wsum[2] + wsum[3];
        atomicAdd(out, t * (1.0f / (float)(BATCH * NPTS)));
    }
}

extern "C" void kernel_launch(void* const* d_in, const int* in_sizes, int n_in,
                              void* d_out, int out_size, void* d_ws, size_t ws_size,
                              hipStream_t stream) {
    const float* input  = (const float*)d_in[0];   // [B, N, 3] fp32
    const float* target = (const float*)d_in[1];   // [B, M, 3] fp32
    float* out  = (float*)d_out;
    float* part = (float*)d_ws;                    // [2][BATCH][NCC][NPTS] = 8 MB

    hipMemsetAsync(out, 0, sizeof(float), stream);

    dim3 grid1(NQC * NCC, BATCH, 2);               // 64 x 8 x 2 = 1024 blocks
    chamfer_min_kernel<<<grid1, dim3(TPB), 0, stream>>>(input, target, part);

    dim3 grid2((2 * BATCH * NPTS) / (TPB * 4));    // 64 blocks
    chamfer_reduce_kernel<<<grid2, dim3(TPB), 0, stream>>>(part, out);
}

// Round 2
// 75.327 us; speedup vs baseline: 1.0971x; 1.0867x over previous
//
#include <hip/hip_runtime.h>
#include <math.h>

#define BATCH 8
#define NPTS  4096
#define TPB   256
#define NCC   4                   // candidate chunks
#define CHUNK (NPTS / NCC)        // 1024 candidates per block
#define ROWS  256                 // query rows per block
#define NRC   (NPTS / ROWS)       // 16 row chunks
#define WROWS 64                  // rows per wave = 2 MFMA row-strips

typedef __bf16 bf16x8 __attribute__((ext_vector_type(8)));
typedef float  f32x16 __attribute__((ext_vector_type(16)));

// One mfma_f32_32x32x16_bf16 per 32x32 tile computes S = ||c||^2 - 2 q.c in
// split precision, packed along K (K=16 >> 3 needed):
//   A[q]: k0-2=hi(q), k3-5=hi(q), k8-10=lo(q), k11=k12=1
//   B[c]: k0-2=hi(-2c), k3-5=lo(-2c), k8-10=hi(-2c), k11=hi(y2), k12=lo(y2)
// => S = hihi + hilo + lohi + y2  (lo*lo ~2^-17 dropped; ~1e-5 abs error).
// Per-pair epilogue is a single fmin. ||q||^2 added in phase 2 (monotone).
__global__ __launch_bounds__(TPB) void chamfer_mfma_kernel(
    const float* __restrict__ input,
    const float* __restrict__ target,
    float* __restrict__ part)     // [2][BATCH][NCC][NPTS] f32 = 2 MB
{
  const int dir = blockIdx.z, b = blockIdx.y;
  const int rc = blockIdx.x & (NRC - 1);
  const int cc = blockIdx.x >> 4;                 // NRC == 16

  const float* __restrict__ qp = (dir ? target : input) + (size_t)b * NPTS * 3;
  const float* __restrict__ cp = (dir ? input  : target) + (size_t)b * NPTS * 3;

  // k-half-major so each lane's B-fragment is ONE ds_read_b128 at
  // consecutive-16B addresses across lanes 0-31 (conflict-free).
  __shared__ bf16x8 sB[2][CHUNK];   // 32 KB
  __shared__ bf16x8 sA[2][ROWS];    //  8 KB

  // --- pack candidates: 4 consecutive cols per thread (12 floats = 3 float4)
  {
    const int c0 = cc * CHUNK + (int)threadIdx.x * 4;
    const float4* __restrict__ cv = (const float4*)(cp + 3 * c0);
    const float4 f0 = cv[0], f1 = cv[1], f2 = cv[2];
    float xs[4] = { f0.x, f0.w, f1.z, f2.y };
    float ys[4] = { f0.y, f1.x, f1.w, f2.z };
    float zs[4] = { f0.z, f1.y, f2.x, f2.w };
    #pragma unroll
    for (int j = 0; j < 4; ++j) {
      const float mx = -2.f * xs[j], my = -2.f * ys[j], mz = -2.f * zs[j];
      const __bf16 hx = (__bf16)mx, hy = (__bf16)my, hz = (__bf16)mz;
      const __bf16 lx = (__bf16)(mx - (float)hx);
      const __bf16 ly = (__bf16)(my - (float)hy);
      const __bf16 lz = (__bf16)(mz - (float)hz);
      const float y2 = fmaf(xs[j], xs[j], fmaf(ys[j], ys[j], zs[j] * zs[j]));
      const __bf16 h2 = (__bf16)y2, l2 = (__bf16)(y2 - (float)h2);
      const __bf16 z0 = (__bf16)0.f;
      bf16x8 v0, v1;
      v0[0]=hx; v0[1]=hy; v0[2]=hz; v0[3]=lx; v0[4]=ly; v0[5]=lz; v0[6]=z0; v0[7]=z0;
      v1[0]=hx; v1[1]=hy; v1[2]=hz; v1[3]=h2; v1[4]=l2; v1[5]=z0; v1[6]=z0; v1[7]=z0;
      sB[0][threadIdx.x * 4 + j] = v0;
      sB[1][threadIdx.x * 4 + j] = v1;
    }
  }
  // --- pack queries: 1 row per thread (ROWS == TPB)
  {
    const int r = rc * ROWS + (int)threadIdx.x;
    const float qx = qp[3*r], qy = qp[3*r+1], qz = qp[3*r+2];
    const __bf16 hx = (__bf16)qx, hy = (__bf16)qy, hz = (__bf16)qz;
    const __bf16 lx = (__bf16)(qx - (float)hx);
    const __bf16 ly = (__bf16)(qy - (float)hy);
    const __bf16 lz = (__bf16)(qz - (float)hz);
    const __bf16 z0 = (__bf16)0.f, o1 = (__bf16)1.f;
    bf16x8 v0, v1;
    v0[0]=hx; v0[1]=hy; v0[2]=hz; v0[3]=hx; v0[4]=hy; v0[5]=hz; v0[6]=z0; v0[7]=z0;
    v1[0]=lx; v1[1]=ly; v1[2]=lz; v1[3]=o1; v1[4]=o1; v1[5]=z0; v1[6]=z0; v1[7]=z0;
    sA[0][threadIdx.x] = v0;
    sA[1][threadIdx.x] = v1;
  }
  __syncthreads();

  const int lane = (int)threadIdx.x & 63;
  const int wave = (int)threadIdx.x >> 6;
  const int half = lane >> 5;          // which K-half this lane supplies
  const int l31  = lane & 31;

  // Each wave owns 64 rows = 2 row-strips; B-frag read amortized over 2 MFMAs.
  const bf16x8 a0 = sA[half][wave * WROWS + l31];
  const bf16x8 a1 = sA[half][wave * WROWS + 32 + l31];

  float rm0[16], rm1[16];
  #pragma unroll
  for (int i = 0; i < 16; ++i) { rm0[i] = 3.4e38f; rm1[i] = 3.4e38f; }

  f32x16 zacc;
  #pragma unroll
  for (int i = 0; i < 16; ++i) zacc[i] = 0.f;

  #pragma unroll 2
  for (int m = 0; m < CHUNK / 32; ++m) {           // 32 col-tiles
    const bf16x8 bf = sB[half][m * 32 + l31];
    const f32x16 d0 = __builtin_amdgcn_mfma_f32_32x32x16_bf16(a0, bf, zacc, 0, 0, 0);
    const f32x16 d1 = __builtin_amdgcn_mfma_f32_32x32x16_bf16(a1, bf, zacc, 0, 0, 0);
    #pragma unroll
    for (int i = 0; i < 16; ++i) {
      rm0[i] = fminf(rm0[i], d0[i]);
      rm1[i] = fminf(rm1[i], d1[i]);
    }
  }

  // Row-min finalize: D layout col=lane&31, row=(reg&3)+8*(reg>>2)+4*(lane>>5).
  // Min across the 32 lanes of each half (xor masks <32 stay in-half).
  float* __restrict__ po = part +
      (((size_t)(dir * BATCH + b) * NCC + cc) * NPTS) + rc * ROWS + wave * WROWS;
  #pragma unroll
  for (int r = 0; r < 16; ++r) {
    float v0 = rm0[r], v1 = rm1[r];
    #pragma unroll
    for (int mk = 1; mk < 32; mk <<= 1) {
      v0 = fminf(v0, __shfl_xor(v0, mk, 64));
      v1 = fminf(v1, __shfl_xor(v1, mk, 64));
    }
    if (l31 == 0) {
      const int row = (r & 3) + 8 * (r >> 2) + 4 * half;
      po[row]      = v0;     // strip 0 (rows 0..31 of wave)
      po[row + 32] = v1;     // strip 1 (rows 32..63 of wave)
    }
  }
}

// Phase 2: min over NCC partials, add ||q||^2, clamp, mean-reduce.
__global__ __launch_bounds__(TPB) void chamfer_reduce_kernel(
    const float* __restrict__ part,
    const float* __restrict__ input,
    const float* __restrict__ target,
    float* __restrict__ out)
{
  const int i = (blockIdx.x * TPB + (int)threadIdx.x) * 4;  // [2][B][NPTS] flat
  const int g = i >> 12;
  const int q = i & (NPTS - 1);
  const int dir = g >> 3, b = g & 7;

  const float* __restrict__ p = part + ((size_t)g * NCC) * NPTS + q;
  float4 mn = *(const float4*)p;
  #pragma unroll
  for (int cc = 1; cc < NCC; ++cc) {
    const float4 t = *(const float4*)(p + (size_t)cc * NPTS);
    mn.x = fminf(mn.x, t.x); mn.y = fminf(mn.y, t.y);
    mn.z = fminf(mn.z, t.z); mn.w = fminf(mn.w, t.w);
  }
  const float* __restrict__ qp =
      (dir ? target : input) + (size_t)b * NPTS * 3 + 3 * q;
  const float4* __restrict__ qv = (const float4*)qp;
  const float4 a = qv[0], c = qv[1], e = qv[2];
  const float x20 = fmaf(a.x, a.x, fmaf(a.y, a.y, a.z * a.z));
  const float x21 = fmaf(a.w, a.w, fmaf(c.x, c.x, c.y * c.y));
  const float x22 = fmaf(c.z, c.z, fmaf(c.w, c.w, e.x * e.x));
  const float x23 = fmaf(e.y, e.y, fmaf(e.z, e.z, e.w * e.w));

  float s = fmaxf(mn.x + x20, 0.f) + fmaxf(mn.y + x21, 0.f) +
            fmaxf(mn.z + x22, 0.f) + fmaxf(mn.w + x23, 0.f);
  #pragma unroll
  for (int off = 32; off > 0; off >>= 1)
    s += __shfl_down(s, off, 64);

  __shared__ float wsum[TPB / 64];
  if ((threadIdx.x & 63) == 0) wsum[threadIdx.x >> 6] = s;
  __syncthreads();
  if (threadIdx.x == 0) {
    const float t = wsum[0] + wsum[1] + wsum[2] + wsum[3];
    atomicAdd(out, t * (1.0f / (float)(BATCH * NPTS)));
  }
}

extern "C" void kernel_launch(void* const* d_in, const int* in_sizes, int n_in,
                              void* d_out, int out_size, void* d_ws, size_t ws_size,
                              hipStream_t stream) {
  const float* input  = (const float*)d_in[0];   // [B, N, 3] fp32
  const float* target = (const float*)d_in[1];   // [B, M, 3] fp32
  float* out  = (float*)d_out;
  float* part = (float*)d_ws;                    // [2][BATCH][NCC][NPTS] = 2 MB

  hipMemsetAsync(out, 0, sizeof(float), stream);

  dim3 grid1(NRC * NCC, BATCH, 2);               // 64 x 8 x 2 = 1024 blocks
  chamfer_mfma_kernel<<<grid1, dim3(TPB), 0, stream>>>(input, target, part);

  dim3 grid2((2 * BATCH * NPTS) / (TPB * 4));    // 64 blocks
  chamfer_reduce_kernel<<<grid2, dim3(TPB), 0, stream>>>(part, input, target, out);
}

// Round 3
// 74.708 us; speedup vs baseline: 1.1061x; 1.0083x over previous
//
#include <hip/hip_runtime.h>
#include <math.h>

#define BATCH 8
#define NPTS  4096
#define TPB   256
#define NCC   4                   // candidate chunks
#define CHUNK (NPTS / NCC)        // 1024 candidates per block
#define ROWS  256                 // query rows per block
#define NRC   (NPTS / ROWS)       // 16 row chunks

typedef __bf16 bf16x8 __attribute__((ext_vector_type(8)));
typedef float  f32x16 __attribute__((ext_vector_type(16)));

// One mfma_f32_32x32x16_bf16 per 32x32 tile computes S = ||c||^2 - 2 q.c in
// split precision packed along K (verified exact-enough: absmax 0 in harness):
//   A[q]: k0-2=hi(q), k3-5=hi(q), k8-10=lo(q), k11=k12=1
//   B[c]: k0-2=hi(-2c), k3-5=lo(-2c), k8-10=hi(-2c), k11=hi(y2), k12=lo(y2)
// Per-pair epilogue is one fmin (min3-fused pairwise). Row finalize is an
// LDS transpose (XOR-swizzled, 2-way conflicts = free) instead of 160
// ds_bpermute shuffles per wave. ||q||^2 + clamp fused here (monotone,
// commutes bit-exactly with the min over cc chunks done in phase 2).
__global__ __launch_bounds__(TPB) void chamfer_mfma_kernel(
    const float* __restrict__ input,
    const float* __restrict__ target,
    float* __restrict__ part)     // [2][BATCH][NCC][NPTS] f32 = 2 MB
{
  const int dir = blockIdx.z, b = blockIdx.y;
  const int rc = blockIdx.x & (NRC - 1);
  const int cc = blockIdx.x >> 4;                 // NRC == 16

  const float* __restrict__ qp = (dir ? target : input) + (size_t)b * NPTS * 3;
  const float* __restrict__ cp = (dir ? input  : target) + (size_t)b * NPTS * 3;

  // k-half-major: each lane's fragment is ONE conflict-free ds_read_b128.
  __shared__ bf16x8 sB[2][CHUNK];   // 32 KB (reused as f32 scratch after loop)
  __shared__ bf16x8 sA[2][ROWS];    //  8 KB

  // --- pack candidates: 4 consecutive cols per thread (12 floats = 3 float4)
  {
    const int c0 = cc * CHUNK + (int)threadIdx.x * 4;
    const float4* __restrict__ cv = (const float4*)(cp + 3 * c0);
    const float4 f0 = cv[0], f1 = cv[1], f2 = cv[2];
    float xs[4] = { f0.x, f0.w, f1.z, f2.y };
    float ys[4] = { f0.y, f1.x, f1.w, f2.z };
    float zs[4] = { f0.z, f1.y, f2.x, f2.w };
    #pragma unroll
    for (int j = 0; j < 4; ++j) {
      const float mx = -2.f * xs[j], my = -2.f * ys[j], mz = -2.f * zs[j];
      const __bf16 hx = (__bf16)mx, hy = (__bf16)my, hz = (__bf16)mz;
      const __bf16 lx = (__bf16)(mx - (float)hx);
      const __bf16 ly = (__bf16)(my - (float)hy);
      const __bf16 lz = (__bf16)(mz - (float)hz);
      const float y2 = fmaf(xs[j], xs[j], fmaf(ys[j], ys[j], zs[j] * zs[j]));
      const __bf16 h2 = (__bf16)y2, l2 = (__bf16)(y2 - (float)h2);
      const __bf16 z0 = (__bf16)0.f;
      bf16x8 v0, v1;
      v0[0]=hx; v0[1]=hy; v0[2]=hz; v0[3]=lx; v0[4]=ly; v0[5]=lz; v0[6]=z0; v0[7]=z0;
      v1[0]=hx; v1[1]=hy; v1[2]=hz; v1[3]=h2; v1[4]=l2; v1[5]=z0; v1[6]=z0; v1[7]=z0;
      sB[0][threadIdx.x * 4 + j] = v0;
      sB[1][threadIdx.x * 4 + j] = v1;
    }
  }
  // --- pack queries: 1 row per thread; keep q in regs for the x2 epilogue
  float qx, qy, qz;
  {
    const int r = rc * ROWS + (int)threadIdx.x;
    qx = qp[3*r]; qy = qp[3*r+1]; qz = qp[3*r+2];
    const __bf16 hx = (__bf16)qx, hy = (__bf16)qy, hz = (__bf16)qz;
    const __bf16 lx = (__bf16)(qx - (float)hx);
    const __bf16 ly = (__bf16)(qy - (float)hy);
    const __bf16 lz = (__bf16)(qz - (float)hz);
    const __bf16 z0 = (__bf16)0.f, o1 = (__bf16)1.f;
    bf16x8 v0, v1;
    v0[0]=hx; v0[1]=hy; v0[2]=hz; v0[3]=hx; v0[4]=hy; v0[5]=hz; v0[6]=z0; v0[7]=z0;
    v1[0]=lx; v1[1]=ly; v1[2]=lz; v1[3]=o1; v1[4]=o1; v1[5]=z0; v1[6]=z0; v1[7]=z0;
    sA[0][threadIdx.x] = v0;
    sA[1][threadIdx.x] = v1;
  }
  __syncthreads();

  const int lane = (int)threadIdx.x & 63;
  const int wave = (int)threadIdx.x >> 6;
  const int half = lane >> 5;          // which K-half this lane supplies
  const int l31  = lane & 31;

  // Each wave owns 64 rows = 2 row-strips; B-frag reads amortized over 4 MFMAs.
  const bf16x8 a0 = sA[half][wave * 64 + l31];
  const bf16x8 a1 = sA[half][wave * 64 + 32 + l31];

  float rm0[16], rm1[16];
  #pragma unroll
  for (int i = 0; i < 16; ++i) { rm0[i] = 3.4e38f; rm1[i] = 3.4e38f; }

  f32x16 zacc;
  #pragma unroll
  for (int i = 0; i < 16; ++i) zacc[i] = 0.f;

  #pragma unroll
  for (int m = 0; m < CHUNK / 32; m += 2) {        // 16 x (2 col-tiles)
    const bf16x8 bfA = sB[half][m * 32 + l31];
    const bf16x8 bfB = sB[half][m * 32 + 32 + l31];
    const f32x16 dA0 = __builtin_amdgcn_mfma_f32_32x32x16_bf16(a0, bfA, zacc, 0, 0, 0);
    const f32x16 dA1 = __builtin_amdgcn_mfma_f32_32x32x16_bf16(a1, bfA, zacc, 0, 0, 0);
    const f32x16 dB0 = __builtin_amdgcn_mfma_f32_32x32x16_bf16(a0, bfB, zacc, 0, 0, 0);
    const f32x16 dB1 = __builtin_amdgcn_mfma_f32_32x32x16_bf16(a1, bfB, zacc, 0, 0, 0);
    #pragma unroll
    for (int i = 0; i < 16; ++i) {
      rm0[i] = fminf(fminf(dA0[i], dB0[i]), rm0[i]);   // -> v_min3_f32
      rm1[i] = fminf(fminf(dA1[i], dB1[i]), rm1[i]);
    }
  }

  // --- row-min finalize via LDS transpose (reuse sB as [256][32] f32,
  // XOR-swizzled col ^= (row&7)<<2 -> writes & reads are 2-way only = free).
  __syncthreads();                     // everyone done reading sB/sA
  float* __restrict__ scr = (float*)sB;
  #pragma unroll
  for (int r = 0; r < 16; ++r) {
    // D layout: row = (r&3) + 8*(r>>2) + 4*half, col = l31.
    const int row0 = wave * 64 + (r & 3) + 8 * (r >> 2) + 4 * half;
    const int sw   = ((row0 & 7) << 2);        // row0&7 == row1&7
    scr[row0 * 32 + (l31 ^ sw)]        = rm0[r];
    scr[(row0 + 32) * 32 + (l31 ^ sw)] = rm1[r];
  }
  __syncthreads();

  // Thread t owns output row t: 8 swizzled b128 reads + min tree.
  const int t = (int)threadIdx.x;
  const float4* __restrict__ rp = (const float4*)(scr + t * 32);
  float mn = 3.4e38f;
  #pragma unroll
  for (int k = 0; k < 8; ++k) {
    const float4 v = rp[k ^ (t & 7)];
    mn = fminf(mn, fminf(fminf(v.x, v.y), fminf(v.z, v.w)));
  }
  const float x2 = fmaf(qx, qx, fmaf(qy, qy, qz * qz));
  part[((size_t)(dir * BATCH + b) * NCC + cc) * NPTS + rc * ROWS + t] =
      fmaxf(mn + x2, 0.f);
}

// Phase 2: pure min over NCC=4 chunk partials (already x2-added + clamped),
// then mean-reduce. Reads 2 MB, coalesced.
__global__ __launch_bounds__(TPB) void chamfer_reduce_kernel(
    const float* __restrict__ part, float* __restrict__ out)
{
  const int i = (blockIdx.x * TPB + (int)threadIdx.x) * 4;  // [2][B][NPTS] flat
  const int g = i >> 12;
  const int q = i & (NPTS - 1);

  const float* __restrict__ p = part + ((size_t)g * NCC) * NPTS + q;
  float4 mn = *(const float4*)p;
  #pragma unroll
  for (int cc = 1; cc < NCC; ++cc) {
    const float4 v = *(const float4*)(p + (size_t)cc * NPTS);
    mn.x = fminf(mn.x, v.x); mn.y = fminf(mn.y, v.y);
    mn.z = fminf(mn.z, v.z); mn.w = fminf(mn.w, v.w);
  }
  float s = mn.x + mn.y + mn.z + mn.w;
  #pragma unroll
  for (int off = 32; off > 0; off >>= 1)
    s += __shfl_down(s, off, 64);

  __shared__ float wsum[TPB / 64];
  if ((threadIdx.x & 63) == 0) wsum[threadIdx.x >> 6] = s;
  __syncthreads();
  if (threadIdx.x == 0) {
    const float v = wsum[0] + wsum[1] + wsum[2] + wsum[3];
    atomicAdd(out, v * (1.0f / (float)(BATCH * NPTS)));
  }
}

extern "C" void kernel_launch(void* const* d_in, const int* in_sizes, int n_in,
                              void* d_out, int out_size, void* d_ws, size_t ws_size,
                              hipStream_t stream) {
  const float* input  = (const float*)d_in[0];   // [B, N, 3] fp32
  const float* target = (const float*)d_in[1];   // [B, M, 3] fp32
  float* out  = (float*)d_out;
  float* part = (float*)d_ws;                    // [2][BATCH][NCC][NPTS] = 2 MB

  hipMemsetAsync(out, 0, sizeof(float), stream);

  dim3 grid1(NRC * NCC, BATCH, 2);               // 64 x 8 x 2 = 1024 blocks
  chamfer_mfma_kernel<<<grid1, dim3(TPB), 0, stream>>>(input, target, part);

  dim3 grid2((2 * BATCH * NPTS) / (TPB * 4));    // 64 blocks
  chamfer_reduce_kernel<<<grid2, dim3(TPB), 0, stream>>>(part, out);
}